// Round 1
// baseline (128.426 us; speedup 1.0000x reference)
//
#include <hip/hip_runtime.h>

// NCC loss, fully fused: per-block (x,y)-tile z-sweep.
// Tile: 32 (x) x 16 (y), z-chunk 20. Halo 4 each side (KS=9).
// Per slice: stage (t,p) halo plane in LDS -> x-filter (9-tap, 5 moments)
// -> y-filter (9-tap) -> per-thread 9-deep z running window -> NCC -> acc.

#define TX 32
#define TY 16
#define ZC 20
#define NZ 160
#define NY 160
#define NX 160

__global__ void ncc_zero_ws(float* ws) { ws[0] = 0.0f; }

__global__ __launch_bounds__(512, 4)
void ncc_fused(const float* __restrict__ pred, const float* __restrict__ target,
               float* __restrict__ ws) {
  // LDS: stage (t,p) 24x40 halo plane; x-filtered moments 24x32
  __shared__ float2 st[24 * 40];    // (t, p)
  __shared__ float4 xf4[24 * 32];   // (sum_t, sum_p, sum_t2, sum_p2)
  __shared__ float  xf1[24 * 32];   // sum_tp
  __shared__ float  wsum[8];

  const int tid = threadIdx.x;
  const int tx = tid & 31;
  const int ty = tid >> 5;          // 0..15

  int b = blockIdx.x;
  const int xt = b % 5;  b /= 5;
  const int yt = b % 10; b /= 10;
  const int zc = b % 8;  b /= 8;
  const int bb = b;                 // batch 0..1

  const int x0 = xt * TX, y0 = yt * TY, z0 = zc * ZC;

  float buf[5][9];                  // z history (static indices via unroll)
  float run[5];                     // z running window sums
  #pragma unroll
  for (int f = 0; f < 5; ++f) {
    run[f] = 0.0f;
    #pragma unroll
    for (int j = 0; j < 9; ++j) buf[f][j] = 0.0f;
  }
  float acc = 0.0f;
  const float inv_kvol = 1.0f / 729.0f;

  for (int s0 = 0; s0 < 28; s0 += 9) {
    #pragma unroll
    for (int p = 0; p < 9; ++p) {
      const int step = s0 + p;          // block-uniform
      if (step < 28) {
        const int zi = z0 - 4 + step;
        const bool zvalid = (zi >= 0) && (zi < NZ);   // block-uniform
        float cur0 = 0.f, cur1 = 0.f, cur2 = 0.f, cur3 = 0.f, cur4 = 0.f;
        if (zvalid) {
          // ---- stage halo plane (zero-padded in x,y) ----
          const int zbase = (bb * NZ + zi) * (NY * NX);
          for (int pos = tid; pos < 24 * 40; pos += 512) {
            const int yy = pos / 40;          // 0..23
            const int xx = pos - yy * 40;     // 0..39
            const int gy = y0 + yy - 4;
            const int gx = x0 + xx - 4;
            float tv = 0.0f, pv = 0.0f;
            if (gy >= 0 && gy < NY && gx >= 0 && gx < NX) {
              const int idx = zbase + gy * NX + gx;
              tv = target[idx];
              pv = pred[idx];
            }
            st[pos] = make_float2(tv, pv);
          }
          __syncthreads();
          // ---- x-filter: 9 taps, compute 5 moments inline ----
          for (int pos = tid; pos < 24 * 32; pos += 512) {
            const int yy = pos >> 5;
            const int xx = pos & 31;
            float s_t = 0.f, s_p = 0.f, s_t2 = 0.f, s_p2 = 0.f, s_tp = 0.f;
            #pragma unroll
            for (int dx = 0; dx < 9; ++dx) {
              const float2 v = st[yy * 40 + xx + dx];
              s_t += v.x;
              s_p += v.y;
              s_t2 = fmaf(v.x, v.x, s_t2);
              s_p2 = fmaf(v.y, v.y, s_p2);
              s_tp = fmaf(v.x, v.y, s_tp);
            }
            xf4[pos] = make_float4(s_t, s_p, s_t2, s_p2);
            xf1[pos] = s_tp;
          }
          __syncthreads();
          // ---- y-filter: 9 taps into registers ----
          #pragma unroll
          for (int dy = 0; dy < 9; ++dy) {
            const float4 a = xf4[(ty + dy) * 32 + tx];
            const float  c = xf1[(ty + dy) * 32 + tx];
            cur0 += a.x; cur1 += a.y; cur2 += a.z; cur3 += a.w; cur4 += c;
          }
        }
        // ---- z running window (slot p is compile-time constant) ----
        run[0] += cur0 - buf[0][p]; buf[0][p] = cur0;
        run[1] += cur1 - buf[1][p]; buf[1][p] = cur1;
        run[2] += cur2 - buf[2][p]; buf[2][p] = cur2;
        run[3] += cur3 - buf[3][p]; buf[3][p] = cur3;
        run[4] += cur4 - buf[4][p]; buf[4][p] = cur4;
        if (step >= 8) {
          // output voxel z = zi - 4 in [z0, z0+ZC)
          const float ts = run[0], psm = run[1], t2 = run[2], p2 = run[3], tp = run[4];
          const float tavg = ts * inv_kvol;
          const float pavg = psm * inv_kvol;
          const float cross = tp - pavg * ts;
          const float tvar  = t2 - tavg * ts;
          const float pvar  = p2 - pavg * psm;
          const float ncc = (cross * cross) / (tvar * pvar + 1e-5f);
          acc += ncc;
        }
      }
    }
  }

  // ---- reduction: wave shuffle -> LDS -> one atomicAdd per block ----
  __syncthreads();
  #pragma unroll
  for (int off = 32; off > 0; off >>= 1)
    acc += __shfl_down(acc, off, 64);
  if ((tid & 63) == 0) wsum[tid >> 6] = acc;
  __syncthreads();
  if (tid == 0) {
    float tot = 0.0f;
    #pragma unroll
    for (int w = 0; w < 8; ++w) tot += wsum[w];
    atomicAdd(ws, tot);
  }
}

__global__ void ncc_finalize(const float* __restrict__ ws, float* __restrict__ out) {
  out[0] = -ws[0] * (1.0f / 8192000.0f);
}

extern "C" void kernel_launch(void* const* d_in, const int* in_sizes, int n_in,
                              void* d_out, int out_size, void* d_ws, size_t ws_size,
                              hipStream_t stream) {
  const float* pred   = (const float*)d_in[0];
  const float* target = (const float*)d_in[1];
  float* out = (float*)d_out;
  float* ws  = (float*)d_ws;

  ncc_zero_ws<<<1, 1, 0, stream>>>(ws);
  // grid: 5 x-tiles * 10 y-tiles * 8 z-chunks * 2 batches = 800 blocks
  ncc_fused<<<800, 512, 0, stream>>>(pred, target, ws);
  ncc_finalize<<<1, 1, 0, stream>>>(ws, out);
}